// Round 15
// baseline (1145.964 us; speedup 1.0000x reference)
//
#include <hip/hip_runtime.h>
#include <stdint.h>
#include <stddef.h>

#define S_LEN 2048
#define B_N   4096
#define T_N   10
#define NCH   128
#define NEG_INF_F (-10000.0f)

template<int CTRL>
__device__ __forceinline__ int dppi(int v) {
    return __builtin_amdgcn_update_dpp(0, v, CTRL, 0xF, 0xF, true);
}

static __device__ __forceinline__ int imin(int a, int b) { return a < b ? a : b; }
static __device__ __forceinline__ int imax(int a, int b) { return a > b ? a : b; }

static __device__ __forceinline__ float vmax3(float a, float b, float c) {
    float d;
    asm("v_max3_f32 %0, %1, %2, %3" : "=v"(d) : "v"(a), "v"(b), "v"(c));
    return d;
}

// one full Viterbi value step as a single asm block: 25 VALU + 1 s_nop, no compiler moves
static __device__ __forceinline__ void vstep(float& fvr, const float (&trr)[16], float f) {
    float c0,c1,c2,c3,c4,c5,c6,c7,c8,c9,c10,c11,c12,c13,c14,c15;
    asm volatile(
        "v_add_f32 %1, %0, %17\n\t"
        "v_add_f32_dpp %2,  %0, %18 row_ror:1  row_mask:0xf bank_mask:0xf\n\t"
        "v_add_f32_dpp %3,  %0, %19 row_ror:2  row_mask:0xf bank_mask:0xf\n\t"
        "v_add_f32_dpp %4,  %0, %20 row_ror:3  row_mask:0xf bank_mask:0xf\n\t"
        "v_add_f32_dpp %5,  %0, %21 row_ror:4  row_mask:0xf bank_mask:0xf\n\t"
        "v_add_f32_dpp %6,  %0, %22 row_ror:5  row_mask:0xf bank_mask:0xf\n\t"
        "v_add_f32_dpp %7,  %0, %23 row_ror:6  row_mask:0xf bank_mask:0xf\n\t"
        "v_add_f32_dpp %8,  %0, %24 row_ror:7  row_mask:0xf bank_mask:0xf\n\t"
        "v_add_f32_dpp %9,  %0, %25 row_ror:8  row_mask:0xf bank_mask:0xf\n\t"
        "v_add_f32_dpp %10, %0, %26 row_ror:9  row_mask:0xf bank_mask:0xf\n\t"
        "v_add_f32_dpp %11, %0, %27 row_ror:10 row_mask:0xf bank_mask:0xf\n\t"
        "v_add_f32_dpp %12, %0, %28 row_ror:11 row_mask:0xf bank_mask:0xf\n\t"
        "v_add_f32_dpp %13, %0, %29 row_ror:12 row_mask:0xf bank_mask:0xf\n\t"
        "v_add_f32_dpp %14, %0, %30 row_ror:13 row_mask:0xf bank_mask:0xf\n\t"
        "v_add_f32_dpp %15, %0, %31 row_ror:14 row_mask:0xf bank_mask:0xf\n\t"
        "v_add_f32_dpp %16, %0, %32 row_ror:15 row_mask:0xf bank_mask:0xf\n\t"
        "v_max3_f32 %1,  %1,  %2,  %3\n\t"
        "v_max3_f32 %4,  %4,  %5,  %6\n\t"
        "v_max3_f32 %7,  %7,  %8,  %9\n\t"
        "v_max3_f32 %10, %10, %11, %12\n\t"
        "v_max3_f32 %13, %13, %14, %15\n\t"
        "v_max3_f32 %1,  %1,  %4,  %7\n\t"
        "v_max3_f32 %10, %10, %13, %16\n\t"
        "v_max_f32 %1, %1, %10\n\t"
        "v_add_f32 %0, %1, %33\n\t"
        "s_nop 1"
        : "+v"(fvr),
          "=&v"(c0), "=&v"(c1), "=&v"(c2),  "=&v"(c3),  "=&v"(c4),  "=&v"(c5),  "=&v"(c6),  "=&v"(c7),
          "=&v"(c8), "=&v"(c9), "=&v"(c10), "=&v"(c11), "=&v"(c12), "=&v"(c13), "=&v"(c14), "=&v"(c15)
        : "v"(trr[0]),  "v"(trr[1]),  "v"(trr[2]),  "v"(trr[3]),
          "v"(trr[4]),  "v"(trr[5]),  "v"(trr[6]),  "v"(trr[7]),
          "v"(trr[8]),  "v"(trr[9]),  "v"(trr[10]), "v"(trr[11]),
          "v"(trr[12]), "v"(trr[13]), "v"(trr[14]), "v"(trr[15]),
          "v"(f));
}

// ---------------- F: value-only forward. 16 lanes/batch, 4 batches/wave, triple-buffered ----------------
__global__ void __launch_bounds__(256) viterbi_fwd(const float* __restrict__ feats,
                                                   const float* __restrict__ trans,
                                                   const int* __restrict__ lengths,
                                                   float* __restrict__ ckpt) {
    const float FNINF = __int_as_float(0xff800000);   // -inf
    const int tid = threadIdx.x;
    const int t   = tid & 15;
    const int b   = blockIdx.x * 16 + (tid >> 4);
    const bool act = (t < T_N);
    const int len = lengths[b];

    int lenW = len;
    lenW = imax(lenW, __shfl_xor(lenW, 16, 64));
    lenW = imax(lenW, __shfl_xor(lenW, 32, 64));
    lenW = __builtin_amdgcn_readfirstlane(lenW);

    // probe actual DPP ror source columns (direction-agnostic)
    int q[16];
    q[0]  = t;
    q[1]  = dppi<0x121>(t);  q[2]  = dppi<0x122>(t);  q[3]  = dppi<0x123>(t);
    q[4]  = dppi<0x124>(t);  q[5]  = dppi<0x125>(t);  q[6]  = dppi<0x126>(t);
    q[7]  = dppi<0x127>(t);  q[8]  = dppi<0x128>(t);  q[9]  = dppi<0x129>(t);
    q[10] = dppi<0x12A>(t);  q[11] = dppi<0x12B>(t);  q[12] = dppi<0x12C>(t);
    q[13] = dppi<0x12D>(t);  q[14] = dppi<0x12E>(t);  q[15] = dppi<0x12F>(t);

    float trr[16];
    #pragma unroll
    for (int r = 0; r < 16; ++r) {
        bool v = act && (q[r] < T_N);
        trr[r] = v ? trans[t * T_N + q[r]] : FNINF;   // tr[t][p_r]
    }

    const float* fptr = feats + (size_t)b * T_N + imin(t, T_N - 1);
    auto ldfeat = [&](int s) -> float {
        return fptr[(size_t)imin(s, S_LEN - 1) * (B_N * T_N)];
    };

    float fvr;
    {
        float finit = (t == 8) ? 0.0f : NEG_INF_F;   // START_TAG = 8
        asm("v_mov_b32 %0, %1\n\ts_nop 1" : "=v"(fvr) : "v"(finit));
    }

    float bA[16], bB[16], bC[16];
    #pragma unroll
    for (int u = 0; u < 16; ++u) bA[u] = ldfeat(u);
    #pragma unroll
    for (int u = 0; u < 16; ++u) bB[u] = ldfeat(16 + u);
    #pragma unroll
    for (int u = 0; u < 16; ++u) bC[u] = ldfeat(32 + u);

    auto step16 = [&](float (&f)[16]) {
        #pragma unroll
        for (int u = 0; u < 16; ++u) vstep(fvr, trr, f[u]);
    };
    auto ckstore = [&](int snext) {
        if (act && snext <= len && snext <= S_LEN - 16)
            ckpt[((size_t)(snext >> 4) * B_N + b) * T_N + t] = fvr;   // fv_all[snext]
    };

    for (int s0 = 0; s0 < lenW; s0 += 48) {
        step16(bA); ckstore(s0 + 16);
        #pragma unroll
        for (int u = 0; u < 16; ++u) bA[u] = ldfeat(s0 + 48 + u);

        step16(bB); ckstore(s0 + 32);
        #pragma unroll
        for (int u = 0; u < 16; ++u) bB[u] = ldfeat(s0 + 64 + u);

        step16(bC); ckstore(s0 + 48);
        #pragma unroll
        for (int u = 0; u < 16; ++u) bC[u] = ldfeat(s0 + 80 + u);
    }
}

// ---------------- A: parallel argmax recompute per (batch, 16-chunk) ----------------
// __launch_bounds__(256,8): cap VGPR at 64 -> 8 waves/SIMD (spill would show in WRITE_SIZE)
__global__ void __launch_bounds__(256, 8) bt_maps(const float* __restrict__ feats,
                                                  const float* __restrict__ trans,
                                                  const int* __restrict__ lengths,
                                                  const float* __restrict__ ckpt,
                                                  unsigned* __restrict__ bpd,
                                                  unsigned char* __restrict__ bpb,
                                                  uint2* __restrict__ gmap,
                                                  float* __restrict__ lastfv) {
    const int c = blockIdx.x >> 4;                          // 0..127
    const int b = ((blockIdx.x & 15) << 8) + threadIdx.x;   // 0..4095
    const int len = lengths[b];
    const int r0 = c * 16;
    const int kl = len - r0;   // lastfv snapshot iteration if 0..16

    if (kl < 0) {   // chunk entirely beyond len
        gmap[(size_t)c * B_N + b] = make_uint2(0x76543210u, 0x98u);
        return;
    }

    float fv[T_N];
    if (c == 0) {
        #pragma unroll
        for (int p = 0; p < T_N; ++p) fv[p] = (p == 8) ? 0.0f : NEG_INF_F;
    } else {
        #pragma unroll
        for (int p = 0; p < T_N; ++p) fv[p] = ckpt[((size_t)c * B_N + b) * T_N + p];
    }

    float* lfp = lastfv + (size_t)b * T_N;
    if (kl == 0) {   // fv here == fv_all[len]; no live rows in this chunk
        #pragma unroll
        for (int n = 0; n < T_N; ++n) lfp[n] = fv[n];
        gmap[(size_t)c * B_N + b] = make_uint2(0x76543210u, 0x98u);
        return;
    }

    const size_t rstride = (size_t)B_N * T_N;
    const float* fbase = feats + (size_t)b * T_N;

    float buf[T_N];
    {   // feat row r0 (r0 < len guaranteed)
        const float2* p2 = (const float2*)(fbase + (size_t)r0 * rstride);
        #pragma unroll
        for (int i = 0; i < 5; ++i) { float2 v = p2[i]; buf[2*i] = v.x; buf[2*i+1] = v.y; }
    }

    unsigned Glo = 0x76543210u, Ghi = 0x98u;

    // k = 0: fv update only (row r0's map belongs to chunk c-1)
    {
        float m[T_N];
        #pragma unroll
        for (int n = 0; n < T_N; ++n) {
            float cd[T_N];
            #pragma unroll
            for (int p = 0; p < T_N; ++p) cd[p] = fv[p] + trans[n * T_N + p];
            float x0 = vmax3(cd[0], cd[1], cd[2]);
            float x1 = vmax3(cd[3], cd[4], cd[5]);
            float x2 = vmax3(cd[6], cd[7], cd[8]);
            m[n] = fmaxf(vmax3(x0, x1, x2), cd[9]);
        }
        #pragma unroll
        for (int n = 0; n < T_N; ++n) fv[n] = m[n] + buf[n];
    }

    #pragma unroll 1
    for (int k = 1; k <= 16; ++k) {
        const int r = r0 + k;
        {   // issue next feat row load at top (hides under the row compute)
            const float2* p2 = (const float2*)(fbase + (size_t)imin(r, S_LEN - 1) * rstride);
            #pragma unroll
            for (int i = 0; i < 5; ++i) { float2 v = p2[i]; buf[2*i] = v.x; buf[2*i+1] = v.y; }
        }
        if (k == kl) {   // fv before this step == fv_all[len]
            #pragma unroll
            for (int n = 0; n < T_N; ++n) lfp[n] = fv[n];
        }
        unsigned mlo = 0, mhi = 0, nGlo = 0, nGhi = 0;
        unsigned long long G64 = ((unsigned long long)Ghi << 32) | Glo;
        float m[T_N];
        #pragma unroll
        for (int n = 0; n < T_N; ++n) {
            float cd[T_N];
            #pragma unroll
            for (int p = 0; p < T_N; ++p) cd[p] = fv[p] + trans[n * T_N + p];
            float x0 = vmax3(cd[0], cd[1], cd[2]);
            float x1 = vmax3(cd[3], cd[4], cd[5]);
            float x2 = vmax3(cd[6], cd[7], cd[8]);
            float mm = fmaxf(vmax3(x0, x1, x2), cd[9]);
            m[n] = mm;
            int ix = 9;
            #pragma unroll
            for (int p = 8; p >= 0; --p) ix = (cd[p] == mm) ? p : ix;   // first tie = min p
            unsigned nib = (unsigned)(G64 >> (ix << 2)) & 15u;
            if (n < 8) { mlo |= (unsigned)ix << (4 * n);       nGlo |= nib << (4 * n); }
            else       { mhi |= (unsigned)ix << (4 * (n - 8)); nGhi |= nib << (4 * (n - 8)); }
        }
        if (r < len) {
            bpd[(size_t)r * B_N + b] = mlo;
            bpb[(size_t)r * B_N + b] = (unsigned char)mhi;
            Glo = nGlo; Ghi = nGhi;
        }
        if (k < 16) {
            #pragma unroll
            for (int n = 0; n < T_N; ++n) fv[n] = m[n] + buf[n];
        }
    }

    gmap[(size_t)c * B_N + b] = make_uint2(Glo, Ghi);
}

// nibble-map apply: next = (w64 >> 4*cur) & 15
static __device__ __forceinline__ int bpapply(uint2 w, int cur) {
    unsigned long long w64 = ((unsigned long long)w.y << 32) | (unsigned long long)w.x;
    return (int)((w64 >> (cur * 4)) & 15ULL);
}

// ---------------- B: terminal score/argmax + compose 128 chunk maps per batch ----------------
__global__ void __launch_bounds__(256) bt_compose(const uint2* __restrict__ gmap,
                                                  const float* __restrict__ lastfv,
                                                  const float* __restrict__ trans,
                                                  unsigned char* __restrict__ entry,
                                                  float* __restrict__ score) {
    const int b = blockIdx.x * 256 + threadIdx.x;

    float term[T_N];
    #pragma unroll
    for (int n = 0; n < T_N; ++n)
        term[n] = lastfv[(size_t)b * T_N + n] + trans[9 * T_N + n];   // STOP row
    float x0 = vmax3(term[0], term[1], term[2]);
    float x1 = vmax3(term[3], term[4], term[5]);
    float x2 = vmax3(term[6], term[7], term[8]);
    float pm = fmaxf(vmax3(x0, x1, x2), term[9]);
    int st = 9;
    #pragma unroll
    for (int n = 8; n >= 0; --n) st = (term[n] == pm) ? n : st;
    score[b] = pm;

    uint2 wA[16], wB[16];
    auto pre = [&](uint2 (&W)[16], int cb) {
        #pragma unroll
        for (int u = 0; u < 16; ++u) W[u] = gmap[(size_t)(cb * 16 + u) * B_N + b];
    };
    auto proc = [&](uint2 (&W)[16], int cb) {
        #pragma unroll
        for (int u = 15; u >= 0; --u) {
            int cc = cb * 16 + u;
            entry[(size_t)cc * B_N + b] = (unsigned char)st;
            st = bpapply(W[u], st);
        }
    };
    pre(wA, 7);
    pre(wB, 6); proc(wA, 7);
    pre(wA, 5); proc(wB, 6);
    pre(wB, 4); proc(wA, 5);
    pre(wA, 3); proc(wB, 4);
    pre(wB, 2); proc(wA, 3);
    pre(wA, 1); proc(wB, 2);
    pre(wB, 0); proc(wA, 1);
    proc(wB, 0);
}

// ---------------- C: follow maps per (batch, chunk) from entry tag, emit path ----------------
__global__ void __launch_bounds__(256) bt_emit(const unsigned* __restrict__ bpd,
                                               const unsigned char* __restrict__ bpb,
                                               const int* __restrict__ lengths,
                                               const unsigned char* __restrict__ entry,
                                               float* __restrict__ opaths) {
    const int c = blockIdx.x >> 4;
    const int b = ((blockIdx.x & 15) << 8) + threadIdx.x;
    const int len = lengths[b];
    float* op = opaths + (size_t)b * S_LEN + c * 16;

    if (c * 16 >= len) {   // fully past len: all zeros, skip map loads
        float4 z = make_float4(0.f, 0.f, 0.f, 0.f);
        #pragma unroll
        for (int qq = 0; qq < 4; ++qq) *(float4*)(op + qq * 4) = z;
        return;
    }

    const int r0 = c * 16 + 1;
    unsigned Wd[16], Wb[16];
    #pragma unroll
    for (int u = 0; u < 16; ++u) {
        int r = r0 + u;
        unsigned d = 0x76543210u, h = 0x98u;   // identity
        if (r < len) { d = bpd[(size_t)r * B_N + b]; h = bpb[(size_t)r * B_N + b]; }
        Wd[u] = d; Wb[u] = h;
    }

    int cur = entry[(size_t)c * B_N + b];
    float buf[16];
    #pragma unroll
    for (int u = 15; u >= 0; --u) {
        unsigned long long w = ((unsigned long long)Wb[u] << 32) | Wd[u];
        cur = (int)((w >> ((cur * 4) & 63)) & 15ULL);
        buf[u] = (c * 16 + u < len) ? (float)cur : 0.0f;
    }
    #pragma unroll
    for (int qq = 0; qq < 4; ++qq)
        *(float4*)(op + qq * 4) = make_float4(buf[qq*4+0], buf[qq*4+1], buf[qq*4+2], buf[qq*4+3]);
}

extern "C" void kernel_launch(void* const* d_in, const int* in_sizes, int n_in,
                              void* d_out, int out_size, void* d_ws, size_t ws_size,
                              hipStream_t stream) {
    const float* feats   = (const float*)d_in[0];
    const float* trans   = (const float*)d_in[1];
    const int*   lengths = (const int*)d_in[2];
    float* out = (float*)d_out;

    // workspace layout (~67.8 MB)
    char* w = (char*)d_ws;
    float*         ckpt  = (float*)w;          w += (size_t)NCH * B_N * T_N * 4;       // 20,971,520
    unsigned*      bpd   = (unsigned*)w;       w += (size_t)(S_LEN + 1) * B_N * 4;     // 33,570,816
    unsigned char* bpb   = (unsigned char*)w;  w += (size_t)(S_LEN + 1) * B_N;         //  8,392,704
    uint2*         gmap  = (uint2*)w;          w += (size_t)NCH * B_N * 8;             //  4,194,304
    unsigned char* entry = (unsigned char*)w;  w += (size_t)NCH * B_N;                 //    524,288
    float*         lastfv = (float*)w;                                                 //    163,840

    viterbi_fwd<<<B_N / 16, 256, 0, stream>>>(feats, trans, lengths, ckpt);
    bt_maps   <<<NCH * (B_N / 256), 256, 0, stream>>>(feats, trans, lengths, ckpt, bpd, bpb, gmap, lastfv);
    bt_compose<<<B_N / 256, 256, 0, stream>>>(gmap, lastfv, trans, entry, out);
    bt_emit   <<<NCH * (B_N / 256), 256, 0, stream>>>(bpd, bpb, lengths, entry, out + B_N);
}

// Round 16
// 313.030 us; speedup vs baseline: 3.6609x; 3.6609x over previous
//
#include <hip/hip_runtime.h>
#include <stdint.h>
#include <stddef.h>

#define S_LEN 2048
#define B_N   4096
#define T_N   10
#define NCH   128
#define NEG_INF_F (-10000.0f)

template<int CTRL>
__device__ __forceinline__ int dppi(int v) {
    return __builtin_amdgcn_update_dpp(0, v, CTRL, 0xF, 0xF, true);
}

static __device__ __forceinline__ int imin(int a, int b) { return a < b ? a : b; }
static __device__ __forceinline__ int imax(int a, int b) { return a > b ? a : b; }

static __device__ __forceinline__ float vmax3(float a, float b, float c) {
    float d;
    asm("v_max3_f32 %0, %1, %2, %3" : "=v"(d) : "v"(a), "v"(b), "v"(c));
    return d;
}

// one full Viterbi value step as a single asm block: 25 VALU + 1 s_nop, no compiler moves
static __device__ __forceinline__ void vstep(float& fvr, const float (&trr)[16], float f) {
    float c0,c1,c2,c3,c4,c5,c6,c7,c8,c9,c10,c11,c12,c13,c14,c15;
    asm volatile(
        "v_add_f32 %1, %0, %17\n\t"
        "v_add_f32_dpp %2,  %0, %18 row_ror:1  row_mask:0xf bank_mask:0xf\n\t"
        "v_add_f32_dpp %3,  %0, %19 row_ror:2  row_mask:0xf bank_mask:0xf\n\t"
        "v_add_f32_dpp %4,  %0, %20 row_ror:3  row_mask:0xf bank_mask:0xf\n\t"
        "v_add_f32_dpp %5,  %0, %21 row_ror:4  row_mask:0xf bank_mask:0xf\n\t"
        "v_add_f32_dpp %6,  %0, %22 row_ror:5  row_mask:0xf bank_mask:0xf\n\t"
        "v_add_f32_dpp %7,  %0, %23 row_ror:6  row_mask:0xf bank_mask:0xf\n\t"
        "v_add_f32_dpp %8,  %0, %24 row_ror:7  row_mask:0xf bank_mask:0xf\n\t"
        "v_add_f32_dpp %9,  %0, %25 row_ror:8  row_mask:0xf bank_mask:0xf\n\t"
        "v_add_f32_dpp %10, %0, %26 row_ror:9  row_mask:0xf bank_mask:0xf\n\t"
        "v_add_f32_dpp %11, %0, %27 row_ror:10 row_mask:0xf bank_mask:0xf\n\t"
        "v_add_f32_dpp %12, %0, %28 row_ror:11 row_mask:0xf bank_mask:0xf\n\t"
        "v_add_f32_dpp %13, %0, %29 row_ror:12 row_mask:0xf bank_mask:0xf\n\t"
        "v_add_f32_dpp %14, %0, %30 row_ror:13 row_mask:0xf bank_mask:0xf\n\t"
        "v_add_f32_dpp %15, %0, %31 row_ror:14 row_mask:0xf bank_mask:0xf\n\t"
        "v_add_f32_dpp %16, %0, %32 row_ror:15 row_mask:0xf bank_mask:0xf\n\t"
        "v_max3_f32 %1,  %1,  %2,  %3\n\t"
        "v_max3_f32 %4,  %4,  %5,  %6\n\t"
        "v_max3_f32 %7,  %7,  %8,  %9\n\t"
        "v_max3_f32 %10, %10, %11, %12\n\t"
        "v_max3_f32 %13, %13, %14, %15\n\t"
        "v_max3_f32 %1,  %1,  %4,  %7\n\t"
        "v_max3_f32 %10, %10, %13, %16\n\t"
        "v_max_f32 %1, %1, %10\n\t"
        "v_add_f32 %0, %1, %33\n\t"
        "s_nop 1"
        : "+v"(fvr),
          "=&v"(c0), "=&v"(c1), "=&v"(c2),  "=&v"(c3),  "=&v"(c4),  "=&v"(c5),  "=&v"(c6),  "=&v"(c7),
          "=&v"(c8), "=&v"(c9), "=&v"(c10), "=&v"(c11), "=&v"(c12), "=&v"(c13), "=&v"(c14), "=&v"(c15)
        : "v"(trr[0]),  "v"(trr[1]),  "v"(trr[2]),  "v"(trr[3]),
          "v"(trr[4]),  "v"(trr[5]),  "v"(trr[6]),  "v"(trr[7]),
          "v"(trr[8]),  "v"(trr[9]),  "v"(trr[10]), "v"(trr[11]),
          "v"(trr[12]), "v"(trr[13]), "v"(trr[14]), "v"(trr[15]),
          "v"(f));
}

// ---------------- F: value-only forward. 16 lanes/batch, 4 batches/wave, triple-buffered ----------------
__global__ void __launch_bounds__(256) viterbi_fwd(const float* __restrict__ feats,
                                                   const float* __restrict__ trans,
                                                   const int* __restrict__ lengths,
                                                   float* __restrict__ ckpt) {
    const float FNINF = __int_as_float(0xff800000);   // -inf
    const int tid = threadIdx.x;
    const int t   = tid & 15;
    const int b   = blockIdx.x * 16 + (tid >> 4);
    const bool act = (t < T_N);
    const int len = lengths[b];

    int lenW = len;
    lenW = imax(lenW, __shfl_xor(lenW, 16, 64));
    lenW = imax(lenW, __shfl_xor(lenW, 32, 64));
    lenW = __builtin_amdgcn_readfirstlane(lenW);

    // probe actual DPP ror source columns (direction-agnostic)
    int q[16];
    q[0]  = t;
    q[1]  = dppi<0x121>(t);  q[2]  = dppi<0x122>(t);  q[3]  = dppi<0x123>(t);
    q[4]  = dppi<0x124>(t);  q[5]  = dppi<0x125>(t);  q[6]  = dppi<0x126>(t);
    q[7]  = dppi<0x127>(t);  q[8]  = dppi<0x128>(t);  q[9]  = dppi<0x129>(t);
    q[10] = dppi<0x12A>(t);  q[11] = dppi<0x12B>(t);  q[12] = dppi<0x12C>(t);
    q[13] = dppi<0x12D>(t);  q[14] = dppi<0x12E>(t);  q[15] = dppi<0x12F>(t);

    float trr[16];
    #pragma unroll
    for (int r = 0; r < 16; ++r) {
        bool v = act && (q[r] < T_N);
        trr[r] = v ? trans[t * T_N + q[r]] : FNINF;   // tr[t][p_r]
    }

    const float* fptr = feats + (size_t)b * T_N + imin(t, T_N - 1);
    auto ldfeat = [&](int s) -> float {
        return fptr[(size_t)imin(s, S_LEN - 1) * (B_N * T_N)];
    };

    float fvr;
    {
        float finit = (t == 8) ? 0.0f : NEG_INF_F;   // START_TAG = 8
        asm("v_mov_b32 %0, %1\n\ts_nop 1" : "=v"(fvr) : "v"(finit));
    }

    float bA[16], bB[16], bC[16];
    #pragma unroll
    for (int u = 0; u < 16; ++u) bA[u] = ldfeat(u);
    #pragma unroll
    for (int u = 0; u < 16; ++u) bB[u] = ldfeat(16 + u);
    #pragma unroll
    for (int u = 0; u < 16; ++u) bC[u] = ldfeat(32 + u);

    auto step16 = [&](float (&f)[16]) {
        #pragma unroll
        for (int u = 0; u < 16; ++u) vstep(fvr, trr, f[u]);
    };
    auto ckstore = [&](int snext) {
        if (act && snext <= len && snext <= S_LEN - 16)
            ckpt[((size_t)(snext >> 4) * B_N + b) * T_N + t] = fvr;   // fv_all[snext]
    };

    for (int s0 = 0; s0 < lenW; s0 += 48) {
        step16(bA); ckstore(s0 + 16);
        #pragma unroll
        for (int u = 0; u < 16; ++u) bA[u] = ldfeat(s0 + 48 + u);

        step16(bB); ckstore(s0 + 32);
        #pragma unroll
        for (int u = 0; u < 16; ++u) bB[u] = ldfeat(s0 + 64 + u);

        step16(bC); ckstore(s0 + 48);
        #pragma unroll
        for (int u = 0; u < 16; ++u) bC[u] = ldfeat(s0 + 80 + u);
    }
}

// ---------------- A: parallel argmax recompute per (batch, 16-chunk) (round-14 exact, no cap) ----------------
__global__ void __launch_bounds__(256) bt_maps(const float* __restrict__ feats,
                                               const float* __restrict__ trans,
                                               const int* __restrict__ lengths,
                                               const float* __restrict__ ckpt,
                                               unsigned* __restrict__ bpd,
                                               unsigned char* __restrict__ bpb,
                                               uint2* __restrict__ gmap,
                                               float* __restrict__ lastfv) {
    const int c = blockIdx.x >> 4;                          // 0..127
    const int b = ((blockIdx.x & 15) << 8) + threadIdx.x;   // 0..4095
    const int len = lengths[b];
    const int r0 = c * 16;
    const int kl = len - r0;   // lastfv snapshot iteration if 0..16

    if (kl < 0) {   // chunk entirely beyond len
        gmap[(size_t)c * B_N + b] = make_uint2(0x76543210u, 0x98u);
        return;
    }

    float fv[T_N];
    if (c == 0) {
        #pragma unroll
        for (int p = 0; p < T_N; ++p) fv[p] = (p == 8) ? 0.0f : NEG_INF_F;
    } else {
        #pragma unroll
        for (int p = 0; p < T_N; ++p) fv[p] = ckpt[((size_t)c * B_N + b) * T_N + p];
    }

    float* lfp = lastfv + (size_t)b * T_N;
    if (kl == 0) {   // fv here == fv_all[len]; no live rows in this chunk
        #pragma unroll
        for (int n = 0; n < T_N; ++n) lfp[n] = fv[n];
        gmap[(size_t)c * B_N + b] = make_uint2(0x76543210u, 0x98u);
        return;
    }

    const size_t rstride = (size_t)B_N * T_N;
    const float* fbase = feats + (size_t)b * T_N;

    float buf[T_N];
    {   // feat row r0 (r0 < len guaranteed)
        const float2* p2 = (const float2*)(fbase + (size_t)r0 * rstride);
        #pragma unroll
        for (int i = 0; i < 5; ++i) { float2 v = p2[i]; buf[2*i] = v.x; buf[2*i+1] = v.y; }
    }

    unsigned Glo = 0x76543210u, Ghi = 0x98u;

    // k = 0: fv update only (row r0's map belongs to chunk c-1)
    {
        float m[T_N];
        #pragma unroll
        for (int n = 0; n < T_N; ++n) {
            float cd[T_N];
            #pragma unroll
            for (int p = 0; p < T_N; ++p) cd[p] = fv[p] + trans[n * T_N + p];
            float x0 = vmax3(cd[0], cd[1], cd[2]);
            float x1 = vmax3(cd[3], cd[4], cd[5]);
            float x2 = vmax3(cd[6], cd[7], cd[8]);
            m[n] = fmaxf(vmax3(x0, x1, x2), cd[9]);
        }
        #pragma unroll
        for (int n = 0; n < T_N; ++n) fv[n] = m[n] + buf[n];
    }

    #pragma unroll 1
    for (int k = 1; k <= 16; ++k) {
        const int r = r0 + k;
        {   // issue next feat row load at top (hides under the row compute)
            const float2* p2 = (const float2*)(fbase + (size_t)imin(r, S_LEN - 1) * rstride);
            #pragma unroll
            for (int i = 0; i < 5; ++i) { float2 v = p2[i]; buf[2*i] = v.x; buf[2*i+1] = v.y; }
        }
        if (k == kl) {   // fv before this step == fv_all[len]
            #pragma unroll
            for (int n = 0; n < T_N; ++n) lfp[n] = fv[n];
        }
        unsigned mlo = 0, mhi = 0, nGlo = 0, nGhi = 0;
        unsigned long long G64 = ((unsigned long long)Ghi << 32) | Glo;
        float m[T_N];
        #pragma unroll
        for (int n = 0; n < T_N; ++n) {
            float cd[T_N];
            #pragma unroll
            for (int p = 0; p < T_N; ++p) cd[p] = fv[p] + trans[n * T_N + p];
            float x0 = vmax3(cd[0], cd[1], cd[2]);
            float x1 = vmax3(cd[3], cd[4], cd[5]);
            float x2 = vmax3(cd[6], cd[7], cd[8]);
            float mm = fmaxf(vmax3(x0, x1, x2), cd[9]);
            m[n] = mm;
            int ix = 9;
            #pragma unroll
            for (int p = 8; p >= 0; --p) ix = (cd[p] == mm) ? p : ix;   // first tie = min p
            unsigned nib = (unsigned)(G64 >> (ix << 2)) & 15u;
            if (n < 8) { mlo |= (unsigned)ix << (4 * n);       nGlo |= nib << (4 * n); }
            else       { mhi |= (unsigned)ix << (4 * (n - 8)); nGhi |= nib << (4 * (n - 8)); }
        }
        if (r < len) {
            bpd[(size_t)r * B_N + b] = mlo;
            bpb[(size_t)r * B_N + b] = (unsigned char)mhi;
            Glo = nGlo; Ghi = nGhi;
        }
        if (k < 16) {
            #pragma unroll
            for (int n = 0; n < T_N; ++n) fv[n] = m[n] + buf[n];
        }
    }

    gmap[(size_t)c * B_N + b] = make_uint2(Glo, Ghi);
}

// nibble-map apply: next = (w64 >> 4*cur) & 15
static __device__ __forceinline__ int bpapply(uint2 w, int cur) {
    unsigned long long w64 = ((unsigned long long)w.y << 32) | (unsigned long long)w.x;
    return (int)((w64 >> (cur * 4)) & 15ULL);
}

// ---------------- B: terminal score/argmax + compose 128 chunk maps per batch ----------------
__global__ void __launch_bounds__(256) bt_compose(const uint2* __restrict__ gmap,
                                                  const float* __restrict__ lastfv,
                                                  const float* __restrict__ trans,
                                                  unsigned char* __restrict__ entry,
                                                  float* __restrict__ score) {
    const int b = blockIdx.x * 256 + threadIdx.x;

    float term[T_N];
    #pragma unroll
    for (int n = 0; n < T_N; ++n)
        term[n] = lastfv[(size_t)b * T_N + n] + trans[9 * T_N + n];   // STOP row
    float x0 = vmax3(term[0], term[1], term[2]);
    float x1 = vmax3(term[3], term[4], term[5]);
    float x2 = vmax3(term[6], term[7], term[8]);
    float pm = fmaxf(vmax3(x0, x1, x2), term[9]);
    int st = 9;
    #pragma unroll
    for (int n = 8; n >= 0; --n) st = (term[n] == pm) ? n : st;
    score[b] = pm;

    uint2 wA[16], wB[16];
    auto pre = [&](uint2 (&W)[16], int cb) {
        #pragma unroll
        for (int u = 0; u < 16; ++u) W[u] = gmap[(size_t)(cb * 16 + u) * B_N + b];
    };
    auto proc = [&](uint2 (&W)[16], int cb) {
        #pragma unroll
        for (int u = 15; u >= 0; --u) {
            int cc = cb * 16 + u;
            entry[(size_t)cc * B_N + b] = (unsigned char)st;
            st = bpapply(W[u], st);
        }
    };
    pre(wA, 7);
    pre(wB, 6); proc(wA, 7);
    pre(wA, 5); proc(wB, 6);
    pre(wB, 4); proc(wA, 5);
    pre(wA, 3); proc(wB, 4);
    pre(wB, 2); proc(wA, 3);
    pre(wA, 1); proc(wB, 2);
    pre(wB, 0); proc(wA, 1);
    proc(wB, 0);
}

// ---------------- C: follow maps per (batch, chunk) from entry tag, emit path ----------------
__global__ void __launch_bounds__(256) bt_emit(const unsigned* __restrict__ bpd,
                                               const unsigned char* __restrict__ bpb,
                                               const int* __restrict__ lengths,
                                               const unsigned char* __restrict__ entry,
                                               float* __restrict__ opaths) {
    const int c = blockIdx.x >> 4;
    const int b = ((blockIdx.x & 15) << 8) + threadIdx.x;
    const int len = lengths[b];
    float* op = opaths + (size_t)b * S_LEN + c * 16;

    if (c * 16 >= len) {   // fully past len: all zeros, skip map loads
        float4 z = make_float4(0.f, 0.f, 0.f, 0.f);
        #pragma unroll
        for (int qq = 0; qq < 4; ++qq) *(float4*)(op + qq * 4) = z;
        return;
    }

    const int r0 = c * 16 + 1;
    unsigned Wd[16], Wb[16];
    #pragma unroll
    for (int u = 0; u < 16; ++u) {
        int r = r0 + u;
        unsigned d = 0x76543210u, h = 0x98u;   // identity
        if (r < len) { d = bpd[(size_t)r * B_N + b]; h = bpb[(size_t)r * B_N + b]; }
        Wd[u] = d; Wb[u] = h;
    }

    int cur = entry[(size_t)c * B_N + b];
    float buf[16];
    #pragma unroll
    for (int u = 15; u >= 0; --u) {
        unsigned long long w = ((unsigned long long)Wb[u] << 32) | Wd[u];
        cur = (int)((w >> ((cur * 4) & 63)) & 15ULL);
        buf[u] = (c * 16 + u < len) ? (float)cur : 0.0f;
    }
    #pragma unroll
    for (int qq = 0; qq < 4; ++qq)
        *(float4*)(op + qq * 4) = make_float4(buf[qq*4+0], buf[qq*4+1], buf[qq*4+2], buf[qq*4+3]);
}

extern "C" void kernel_launch(void* const* d_in, const int* in_sizes, int n_in,
                              void* d_out, int out_size, void* d_ws, size_t ws_size,
                              hipStream_t stream) {
    const float* feats   = (const float*)d_in[0];
    const float* trans   = (const float*)d_in[1];
    const int*   lengths = (const int*)d_in[2];
    float* out = (float*)d_out;

    // workspace layout (~67.8 MB)
    char* w = (char*)d_ws;
    float*         ckpt  = (float*)w;          w += (size_t)NCH * B_N * T_N * 4;       // 20,971,520
    unsigned*      bpd   = (unsigned*)w;       w += (size_t)(S_LEN + 1) * B_N * 4;     // 33,570,816
    unsigned char* bpb   = (unsigned char*)w;  w += (size_t)(S_LEN + 1) * B_N;         //  8,392,704
    uint2*         gmap  = (uint2*)w;          w += (size_t)NCH * B_N * 8;             //  4,194,304
    unsigned char* entry = (unsigned char*)w;  w += (size_t)NCH * B_N;                 //    524,288
    float*         lastfv = (float*)w;                                                 //    163,840

    viterbi_fwd<<<B_N / 16, 256, 0, stream>>>(feats, trans, lengths, ckpt);
    bt_maps   <<<NCH * (B_N / 256), 256, 0, stream>>>(feats, trans, lengths, ckpt, bpd, bpb, gmap, lastfv);
    bt_compose<<<B_N / 256, 256, 0, stream>>>(gmap, lastfv, trans, entry, out);
    bt_emit   <<<NCH * (B_N / 256), 256, 0, stream>>>(bpd, bpb, lengths, entry, out + B_N);
}

// Round 17
// 312.572 us; speedup vs baseline: 3.6662x; 1.0015x over previous
//
#include <hip/hip_runtime.h>
#include <stdint.h>
#include <stddef.h>

#define S_LEN 2048
#define B_N   4096
#define T_N   10
#define NCH   128
#define NEG_INF_F (-10000.0f)

template<int CTRL>
__device__ __forceinline__ int dppi(int v) {
    return __builtin_amdgcn_update_dpp(0, v, CTRL, 0xF, 0xF, true);
}

static __device__ __forceinline__ int imin(int a, int b) { return a < b ? a : b; }
static __device__ __forceinline__ int imax(int a, int b) { return a > b ? a : b; }

static __device__ __forceinline__ float vmax3(float a, float b, float c) {
    float d;
    asm("v_max3_f32 %0, %1, %2, %3" : "=v"(d) : "v"(a), "v"(b), "v"(c));
    return d;
}

// one full Viterbi value step as a single asm block: 25 VALU + 1 s_nop, no compiler moves
static __device__ __forceinline__ void vstep(float& fvr, const float (&trr)[16], float f) {
    float c0,c1,c2,c3,c4,c5,c6,c7,c8,c9,c10,c11,c12,c13,c14,c15;
    asm volatile(
        "v_add_f32 %1, %0, %17\n\t"
        "v_add_f32_dpp %2,  %0, %18 row_ror:1  row_mask:0xf bank_mask:0xf\n\t"
        "v_add_f32_dpp %3,  %0, %19 row_ror:2  row_mask:0xf bank_mask:0xf\n\t"
        "v_add_f32_dpp %4,  %0, %20 row_ror:3  row_mask:0xf bank_mask:0xf\n\t"
        "v_add_f32_dpp %5,  %0, %21 row_ror:4  row_mask:0xf bank_mask:0xf\n\t"
        "v_add_f32_dpp %6,  %0, %22 row_ror:5  row_mask:0xf bank_mask:0xf\n\t"
        "v_add_f32_dpp %7,  %0, %23 row_ror:6  row_mask:0xf bank_mask:0xf\n\t"
        "v_add_f32_dpp %8,  %0, %24 row_ror:7  row_mask:0xf bank_mask:0xf\n\t"
        "v_add_f32_dpp %9,  %0, %25 row_ror:8  row_mask:0xf bank_mask:0xf\n\t"
        "v_add_f32_dpp %10, %0, %26 row_ror:9  row_mask:0xf bank_mask:0xf\n\t"
        "v_add_f32_dpp %11, %0, %27 row_ror:10 row_mask:0xf bank_mask:0xf\n\t"
        "v_add_f32_dpp %12, %0, %28 row_ror:11 row_mask:0xf bank_mask:0xf\n\t"
        "v_add_f32_dpp %13, %0, %29 row_ror:12 row_mask:0xf bank_mask:0xf\n\t"
        "v_add_f32_dpp %14, %0, %30 row_ror:13 row_mask:0xf bank_mask:0xf\n\t"
        "v_add_f32_dpp %15, %0, %31 row_ror:14 row_mask:0xf bank_mask:0xf\n\t"
        "v_add_f32_dpp %16, %0, %32 row_ror:15 row_mask:0xf bank_mask:0xf\n\t"
        "v_max3_f32 %1,  %1,  %2,  %3\n\t"
        "v_max3_f32 %4,  %4,  %5,  %6\n\t"
        "v_max3_f32 %7,  %7,  %8,  %9\n\t"
        "v_max3_f32 %10, %10, %11, %12\n\t"
        "v_max3_f32 %13, %13, %14, %15\n\t"
        "v_max3_f32 %1,  %1,  %4,  %7\n\t"
        "v_max3_f32 %10, %10, %13, %16\n\t"
        "v_max_f32 %1, %1, %10\n\t"
        "v_add_f32 %0, %1, %33\n\t"
        "s_nop 1"
        : "+v"(fvr),
          "=&v"(c0), "=&v"(c1), "=&v"(c2),  "=&v"(c3),  "=&v"(c4),  "=&v"(c5),  "=&v"(c6),  "=&v"(c7),
          "=&v"(c8), "=&v"(c9), "=&v"(c10), "=&v"(c11), "=&v"(c12), "=&v"(c13), "=&v"(c14), "=&v"(c15)
        : "v"(trr[0]),  "v"(trr[1]),  "v"(trr[2]),  "v"(trr[3]),
          "v"(trr[4]),  "v"(trr[5]),  "v"(trr[6]),  "v"(trr[7]),
          "v"(trr[8]),  "v"(trr[9]),  "v"(trr[10]), "v"(trr[11]),
          "v"(trr[12]), "v"(trr[13]), "v"(trr[14]), "v"(trr[15]),
          "v"(f));
}

// ---------------- F: value-only forward. 16 lanes/batch, 4 batches/wave, triple-buffered ----------------
__global__ void __launch_bounds__(256) viterbi_fwd(const float* __restrict__ feats,
                                                   const float* __restrict__ trans,
                                                   const int* __restrict__ lengths,
                                                   float* __restrict__ ckpt) {
    const float FNINF = __int_as_float(0xff800000);   // -inf
    const int tid = threadIdx.x;
    const int t   = tid & 15;
    const int b   = blockIdx.x * 16 + (tid >> 4);
    const bool act = (t < T_N);
    const int len = lengths[b];

    int lenW = len;
    lenW = imax(lenW, __shfl_xor(lenW, 16, 64));
    lenW = imax(lenW, __shfl_xor(lenW, 32, 64));
    lenW = __builtin_amdgcn_readfirstlane(lenW);

    // probe actual DPP ror source columns (direction-agnostic)
    int q[16];
    q[0]  = t;
    q[1]  = dppi<0x121>(t);  q[2]  = dppi<0x122>(t);  q[3]  = dppi<0x123>(t);
    q[4]  = dppi<0x124>(t);  q[5]  = dppi<0x125>(t);  q[6]  = dppi<0x126>(t);
    q[7]  = dppi<0x127>(t);  q[8]  = dppi<0x128>(t);  q[9]  = dppi<0x129>(t);
    q[10] = dppi<0x12A>(t);  q[11] = dppi<0x12B>(t);  q[12] = dppi<0x12C>(t);
    q[13] = dppi<0x12D>(t);  q[14] = dppi<0x12E>(t);  q[15] = dppi<0x12F>(t);

    float trr[16];
    #pragma unroll
    for (int r = 0; r < 16; ++r) {
        bool v = act && (q[r] < T_N);
        trr[r] = v ? trans[t * T_N + q[r]] : FNINF;   // tr[t][p_r]
    }

    const float* fptr = feats + (size_t)b * T_N + imin(t, T_N - 1);
    auto ldfeat = [&](int s) -> float {
        return fptr[(size_t)imin(s, S_LEN - 1) * (B_N * T_N)];
    };

    float fvr;
    {
        float finit = (t == 8) ? 0.0f : NEG_INF_F;   // START_TAG = 8
        asm("v_mov_b32 %0, %1\n\ts_nop 1" : "=v"(fvr) : "v"(finit));
    }

    float bA[16], bB[16], bC[16];
    #pragma unroll
    for (int u = 0; u < 16; ++u) bA[u] = ldfeat(u);
    #pragma unroll
    for (int u = 0; u < 16; ++u) bB[u] = ldfeat(16 + u);
    #pragma unroll
    for (int u = 0; u < 16; ++u) bC[u] = ldfeat(32 + u);

    auto step16 = [&](float (&f)[16]) {
        #pragma unroll
        for (int u = 0; u < 16; ++u) vstep(fvr, trr, f[u]);
    };
    auto ckstore = [&](int snext) {
        if (act && snext <= len && snext <= S_LEN - 16)
            ckpt[((size_t)(snext >> 4) * B_N + b) * T_N + t] = fvr;   // fv_all[snext]
    };

    for (int s0 = 0; s0 < lenW; s0 += 48) {
        step16(bA); ckstore(s0 + 16);
        #pragma unroll
        for (int u = 0; u < 16; ++u) bA[u] = ldfeat(s0 + 48 + u);

        step16(bB); ckstore(s0 + 32);
        #pragma unroll
        for (int u = 0; u < 16; ++u) bB[u] = ldfeat(s0 + 64 + u);

        step16(bC); ckstore(s0 + 48);
        #pragma unroll
        for (int u = 0; u < 16; ++u) bC[u] = ldfeat(s0 + 80 + u);
    }
}

// ---------------- A: parallel argmax recompute per (batch, 16-chunk) ----------------
// 3-buffer rotation, feat row k loaded 2 iterations before consumption (~920cy cover).
__global__ void __launch_bounds__(256) bt_maps(const float* __restrict__ feats,
                                               const float* __restrict__ trans,
                                               const int* __restrict__ lengths,
                                               const float* __restrict__ ckpt,
                                               unsigned* __restrict__ bpd,
                                               unsigned char* __restrict__ bpb,
                                               uint2* __restrict__ gmap,
                                               float* __restrict__ lastfv) {
    const int c = blockIdx.x >> 4;                          // 0..127
    const int b = ((blockIdx.x & 15) << 8) + threadIdx.x;   // 0..4095
    const int len = lengths[b];
    const int r0 = c * 16;
    const int kl = len - r0;   // lastfv snapshot iteration if 0..16

    if (kl < 0) {   // chunk entirely beyond len
        gmap[(size_t)c * B_N + b] = make_uint2(0x76543210u, 0x98u);
        return;
    }

    float fv[T_N];
    if (c == 0) {
        #pragma unroll
        for (int p = 0; p < T_N; ++p) fv[p] = (p == 8) ? 0.0f : NEG_INF_F;
    } else {
        #pragma unroll
        for (int p = 0; p < T_N; ++p) fv[p] = ckpt[((size_t)c * B_N + b) * T_N + p];
    }

    float* lfp = lastfv + (size_t)b * T_N;
    if (kl == 0) {   // fv here == fv_all[len]; no live rows in this chunk
        #pragma unroll
        for (int n = 0; n < T_N; ++n) lfp[n] = fv[n];
        gmap[(size_t)c * B_N + b] = make_uint2(0x76543210u, 0x98u);
        return;
    }

    const size_t rstride = (size_t)B_N * T_N;
    const float* fbase = feats + (size_t)b * T_N;

    float A[T_N], Bu[T_N], Cu[T_N];
    auto ldrow = [&](float (&Bf)[T_N], int r) {
        const float2* p2 = (const float2*)(fbase + (size_t)imin(r, S_LEN - 1) * rstride);
        #pragma unroll
        for (int i = 0; i < 5; ++i) { float2 v = p2[i]; Bf[2*i] = v.x; Bf[2*i+1] = v.y; }
    };

    ldrow(A, r0);        // row 0 of chunk
    ldrow(Bu, r0 + 1);   // row 1

    unsigned Glo = 0x76543210u, Ghi = 0x98u;

    // k = 0: fv update only (row r0's map belongs to chunk c-1)
    {
        ldrow(Cu, r0 + 2);   // distance-2 prefetch
        float m[T_N];
        #pragma unroll
        for (int n = 0; n < T_N; ++n) {
            float cd[T_N];
            #pragma unroll
            for (int p = 0; p < T_N; ++p) cd[p] = fv[p] + trans[n * T_N + p];
            float x0 = vmax3(cd[0], cd[1], cd[2]);
            float x1 = vmax3(cd[3], cd[4], cd[5]);
            float x2 = vmax3(cd[6], cd[7], cd[8]);
            m[n] = fmaxf(vmax3(x0, x1, x2), cd[9]);
        }
        #pragma unroll
        for (int n = 0; n < T_N; ++n) fv[n] = m[n] + A[n];
    }

    auto body = [&](int k, const float (&use)[T_N], bool dofv) {
        if (k == kl) {   // fv before this step == fv_all[len]
            #pragma unroll
            for (int n = 0; n < T_N; ++n) lfp[n] = fv[n];
        }
        unsigned mlo = 0, mhi = 0, nGlo = 0, nGhi = 0;
        unsigned long long G64 = ((unsigned long long)Ghi << 32) | Glo;
        float m[T_N];
        #pragma unroll
        for (int n = 0; n < T_N; ++n) {
            float cd[T_N];
            #pragma unroll
            for (int p = 0; p < T_N; ++p) cd[p] = fv[p] + trans[n * T_N + p];
            float x0 = vmax3(cd[0], cd[1], cd[2]);
            float x1 = vmax3(cd[3], cd[4], cd[5]);
            float x2 = vmax3(cd[6], cd[7], cd[8]);
            float mm = fmaxf(vmax3(x0, x1, x2), cd[9]);
            m[n] = mm;
            int ix = 9;
            #pragma unroll
            for (int p = 8; p >= 0; --p) ix = (cd[p] == mm) ? p : ix;   // first tie = min p
            unsigned nib = (unsigned)(G64 >> (ix << 2)) & 15u;
            if (n < 8) { mlo |= (unsigned)ix << (4 * n);       nGlo |= nib << (4 * n); }
            else       { mhi |= (unsigned)ix << (4 * (n - 8)); nGhi |= nib << (4 * (n - 8)); }
        }
        const int r = r0 + k;
        if (r < len) {
            bpd[(size_t)r * B_N + b] = mlo;
            bpb[(size_t)r * B_N + b] = (unsigned char)mhi;
            Glo = nGlo; Ghi = nGhi;
        }
        if (dofv) {
            #pragma unroll
            for (int n = 0; n < T_N; ++n) fv[n] = m[n] + use[n];
        }
    };

    // rows k=1..15 consumed, distance-2 prefetch; k=16 map-only
    ldrow(A,  r0 + 3);  body(1,  Bu, true);
    ldrow(Bu, r0 + 4);  body(2,  Cu, true);
    ldrow(Cu, r0 + 5);  body(3,  A,  true);
    ldrow(A,  r0 + 6);  body(4,  Bu, true);
    ldrow(Bu, r0 + 7);  body(5,  Cu, true);
    ldrow(Cu, r0 + 8);  body(6,  A,  true);
    ldrow(A,  r0 + 9);  body(7,  Bu, true);
    ldrow(Bu, r0 + 10); body(8,  Cu, true);
    ldrow(Cu, r0 + 11); body(9,  A,  true);
    ldrow(A,  r0 + 12); body(10, Bu, true);
    ldrow(Bu, r0 + 13); body(11, Cu, true);
    ldrow(Cu, r0 + 14); body(12, A,  true);
    ldrow(A,  r0 + 15); body(13, Bu, true);
    body(14, Cu, true);
    body(15, A,  true);
    body(16, A,  false);   // map only, no fv update

    gmap[(size_t)c * B_N + b] = make_uint2(Glo, Ghi);
}

// nibble-map apply: next = (w64 >> 4*cur) & 15
static __device__ __forceinline__ int bpapply(uint2 w, int cur) {
    unsigned long long w64 = ((unsigned long long)w.y << 32) | (unsigned long long)w.x;
    return (int)((w64 >> (cur * 4)) & 15ULL);
}

// ---------------- B: terminal score/argmax + compose 128 chunk maps per batch ----------------
__global__ void __launch_bounds__(256) bt_compose(const uint2* __restrict__ gmap,
                                                  const float* __restrict__ lastfv,
                                                  const float* __restrict__ trans,
                                                  unsigned char* __restrict__ entry,
                                                  float* __restrict__ score) {
    const int b = blockIdx.x * 256 + threadIdx.x;

    float term[T_N];
    #pragma unroll
    for (int n = 0; n < T_N; ++n)
        term[n] = lastfv[(size_t)b * T_N + n] + trans[9 * T_N + n];   // STOP row
    float x0 = vmax3(term[0], term[1], term[2]);
    float x1 = vmax3(term[3], term[4], term[5]);
    float x2 = vmax3(term[6], term[7], term[8]);
    float pm = fmaxf(vmax3(x0, x1, x2), term[9]);
    int st = 9;
    #pragma unroll
    for (int n = 8; n >= 0; --n) st = (term[n] == pm) ? n : st;
    score[b] = pm;

    uint2 wA[16], wB[16];
    auto pre = [&](uint2 (&W)[16], int cb) {
        #pragma unroll
        for (int u = 0; u < 16; ++u) W[u] = gmap[(size_t)(cb * 16 + u) * B_N + b];
    };
    auto proc = [&](uint2 (&W)[16], int cb) {
        #pragma unroll
        for (int u = 15; u >= 0; --u) {
            int cc = cb * 16 + u;
            entry[(size_t)cc * B_N + b] = (unsigned char)st;
            st = bpapply(W[u], st);
        }
    };
    pre(wA, 7);
    pre(wB, 6); proc(wA, 7);
    pre(wA, 5); proc(wB, 6);
    pre(wB, 4); proc(wA, 5);
    pre(wA, 3); proc(wB, 4);
    pre(wB, 2); proc(wA, 3);
    pre(wA, 1); proc(wB, 2);
    pre(wB, 0); proc(wA, 1);
    proc(wB, 0);
}

// ---------------- C: follow maps per (batch, chunk) from entry tag, emit path ----------------
__global__ void __launch_bounds__(256) bt_emit(const unsigned* __restrict__ bpd,
                                               const unsigned char* __restrict__ bpb,
                                               const int* __restrict__ lengths,
                                               const unsigned char* __restrict__ entry,
                                               float* __restrict__ opaths) {
    const int c = blockIdx.x >> 4;
    const int b = ((blockIdx.x & 15) << 8) + threadIdx.x;
    const int len = lengths[b];
    float* op = opaths + (size_t)b * S_LEN + c * 16;

    if (c * 16 >= len) {   // fully past len: all zeros, skip map loads
        float4 z = make_float4(0.f, 0.f, 0.f, 0.f);
        #pragma unroll
        for (int qq = 0; qq < 4; ++qq) *(float4*)(op + qq * 4) = z;
        return;
    }

    const int r0 = c * 16 + 1;
    unsigned Wd[16], Wb[16];
    #pragma unroll
    for (int u = 0; u < 16; ++u) {
        int r = r0 + u;
        unsigned d = 0x76543210u, h = 0x98u;   // identity
        if (r < len) { d = bpd[(size_t)r * B_N + b]; h = bpb[(size_t)r * B_N + b]; }
        Wd[u] = d; Wb[u] = h;
    }

    int cur = entry[(size_t)c * B_N + b];
    float buf[16];
    #pragma unroll
    for (int u = 15; u >= 0; --u) {
        unsigned long long w = ((unsigned long long)Wb[u] << 32) | Wd[u];
        cur = (int)((w >> ((cur * 4) & 63)) & 15ULL);
        buf[u] = (c * 16 + u < len) ? (float)cur : 0.0f;
    }
    #pragma unroll
    for (int qq = 0; qq < 4; ++qq)
        *(float4*)(op + qq * 4) = make_float4(buf[qq*4+0], buf[qq*4+1], buf[qq*4+2], buf[qq*4+3]);
}

extern "C" void kernel_launch(void* const* d_in, const int* in_sizes, int n_in,
                              void* d_out, int out_size, void* d_ws, size_t ws_size,
                              hipStream_t stream) {
    const float* feats   = (const float*)d_in[0];
    const float* trans   = (const float*)d_in[1];
    const int*   lengths = (const int*)d_in[2];
    float* out = (float*)d_out;

    // workspace layout (~67.8 MB)
    char* w = (char*)d_ws;
    float*         ckpt  = (float*)w;          w += (size_t)NCH * B_N * T_N * 4;       // 20,971,520
    unsigned*      bpd   = (unsigned*)w;       w += (size_t)(S_LEN + 1) * B_N * 4;     // 33,570,816
    unsigned char* bpb   = (unsigned char*)w;  w += (size_t)(S_LEN + 1) * B_N;         //  8,392,704
    uint2*         gmap  = (uint2*)w;          w += (size_t)NCH * B_N * 8;             //  4,194,304
    unsigned char* entry = (unsigned char*)w;  w += (size_t)NCH * B_N;                 //    524,288
    float*         lastfv = (float*)w;                                                 //    163,840

    viterbi_fwd<<<B_N / 16, 256, 0, stream>>>(feats, trans, lengths, ckpt);
    bt_maps   <<<NCH * (B_N / 256), 256, 0, stream>>>(feats, trans, lengths, ckpt, bpd, bpb, gmap, lastfv);
    bt_compose<<<B_N / 256, 256, 0, stream>>>(gmap, lastfv, trans, entry, out);
    bt_emit   <<<NCH * (B_N / 256), 256, 0, stream>>>(bpd, bpb, lengths, entry, out + B_N);
}